// Round 8
// baseline (343.429 us; speedup 1.0000x reference)
//
#include <hip/hip_runtime.h>

// x [B=16, N=1024, F=256] fp32.  Algebra (alpha folded away):
//   WfA = pack(Wa^T@Wb), WfC = pack(Wr@Wu), bc = Wr@bu    (prep)
//   ab = x@Wab^T, U2 = x@Wcb^T+bc (proj; outputs fragment-PACKED over n)
//   d[m] = x[m]·ab[m]
//   G[b][j][f] = sum_n U2T[b,j,n]*abT[b,f,n]   (m2; G fragment-PACKED over f)
//   out[m,j] = (x[m,:]·G[b][j,:] - d[m]*U2[m,j])/N + x[m,j]  (final; U2 fused inline)
// Round-8: single fused kernel, per-batch producer/consumer counters (NOT grid
// barriers).  Relaxed spin + s_sleep + single acquire at success (R2's per-poll
// acquire caused the L2-invalidate storm).  Work skewed so batch pipelines:
// proj strips (1:1 blocks) -> m2 tiles on the NEXT 64-block group -> final on
// the proj group.  launch_bounds(256,4), LDS 17.7KB -> all 1024 co-resident.

typedef __bf16 bf16;
typedef float floatx4 __attribute__((ext_vector_type(4)));
typedef bf16 bf16x8 __attribute__((ext_vector_type(8)));

constexpr int FD = 256;
constexpr int NB = 16;
constexpr int NN = 1024;
constexpr int RR = NB * NN;       // 16384

__device__ __forceinline__ bf16x8 cvt8(float4 a, float4 b) {
    bf16x8 o = { (bf16)a.x, (bf16)a.y, (bf16)a.z, (bf16)a.w,
                 (bf16)b.x, (bf16)b.y, (bf16)b.z, (bf16)b.w };
    return o;
}

// fragment-packed index for a [256 rows][256 k] operand (1KB burst per chunk)
__device__ __forceinline__ int pk(int r, int k) {
    return ((r >> 4) * 8 + (k >> 5)) * 512 + (((k >> 3) & 3) * 16 + (r & 15)) * 8 + (k & 7);
}

// ---------------- K1: prep (also zeroes the 32 pipeline counters) ----------------
__global__ __launch_bounds__(256)
void prep(const float* __restrict__ Wa, const float* __restrict__ Wb,
          const float* __restrict__ Wu, const float* __restrict__ bu,
          const float* __restrict__ Wr,
          bf16* __restrict__ WfC, bf16* __restrict__ WfA, float* __restrict__ bc,
          int* __restrict__ cnt)
{
    const int blk = blockIdx.x, tid = threadIdx.x;
    if (blk < 256) {
        const int j = blk;
        float acc = 0.0f;
        for (int g = 0; g < FD; g += 4) {
            float4 wr = *(const float4*)&Wr[j * FD + g];
            acc += wr.x * Wu[g * FD + tid] + wr.y * Wu[(g + 1) * FD + tid]
                 + wr.z * Wu[(g + 2) * FD + tid] + wr.w * Wu[(g + 3) * FD + tid];
        }
        WfC[pk(j, tid)] = (bf16)acc;
    } else if (blk == 256) {
        if (tid < 32) cnt[tid] = 0;    // cnt_p[16] + cnt_m[16]
        float s = 0.0f;
        for (int g = 0; g < FD; g++) s += Wr[tid * FD + g] * bu[g];
        bc[tid] = s;
    } else {
        const int f = blk - 257;
        float acc = 0.0f;
        for (int k = 0; k < FD; k += 4) {
            acc += Wa[k * FD + f] * Wb[k * FD + tid]
                 + Wa[(k + 1) * FD + f] * Wb[(k + 1) * FD + tid]
                 + Wa[(k + 2) * FD + f] * Wb[(k + 2) * FD + tid]
                 + Wa[(k + 3) * FD + f] * Wb[(k + 3) * FD + tid];
        }
        WfA[pk(f, tid)] = (bf16)acc;
    }
}

// ---- wait helper: relaxed polls, one acquire on success ----
__device__ __forceinline__ void wait_for(int* c, int target) {
    if (threadIdx.x == 0) {
        while (__hip_atomic_load(c, __ATOMIC_RELAXED, __HIP_MEMORY_SCOPE_AGENT) < target)
            __builtin_amdgcn_s_sleep(16);
        (void)__hip_atomic_load(c, __ATOMIC_ACQUIRE, __HIP_MEMORY_SCOPE_AGENT);
    }
    __syncthreads();
}
__device__ __forceinline__ void publish(int* c) {
    __syncthreads();
    if (threadIdx.x == 0) {
        __threadfence();
        __hip_atomic_fetch_add(c, 1, __ATOMIC_RELEASE, __HIP_MEMORY_SCOPE_AGENT);
    }
}

// ---------------- fused: proj -> (per-batch) m2 -> (per-batch) final ----------------
__global__ __launch_bounds__(256, 4)
void fused(const float* __restrict__ x,
           const bf16* __restrict__ WfA, const bf16* __restrict__ WfC,
           bf16* __restrict__ abTp, bf16* __restrict__ U2Tp, bf16* __restrict__ Gp,
           const float* __restrict__ bc, float* __restrict__ dvec,
           float* __restrict__ out, int* __restrict__ cnt)
{
    __shared__ __align__(16) bf16 TrT[256 * 24];
    __shared__ float dsum[4][16];
    __shared__ __align__(16) bf16 Tr[64][40];

    int* cnt_p = cnt;
    int* cnt_m = cnt + 16;

    const int bid = blockIdx.x;
    const int tid = threadIdx.x;
    const int wave = tid >> 6, lane = tid & 63;
    const int q = lane >> 4, l16 = lane & 15;

    // ================= Phase 1: proj strip bid =================
    {
        const int bm = bid * 16;
        const int b = bm >> 10, n0 = bm & (NN - 1);

        const float* xr = x + (size_t)(bm + l16) * FD;
        bf16x8 af[8];
        #pragma unroll
        for (int ks = 0; ks < 8; ks++) {
            const float* p = xr + ks * 32 + q * 8;
            af[ks] = cvt8(*(const float4*)p, *(const float4*)(p + 4));
        }

        floatx4 acc[2][4] = {};
        #pragma unroll
        for (int nj = 0; nj < 4; nj++) {
            const bf16* pA = WfA + (size_t)((wave * 4 + nj) * 8) * 512 + lane * 8;
            const bf16* pC = WfC + (size_t)((wave * 4 + nj) * 8) * 512 + lane * 8;
            #pragma unroll
            for (int ks = 0; ks < 8; ks++) {
                bf16x8 b0 = *(const bf16x8*)(pA + ks * 512);
                bf16x8 b1 = *(const bf16x8*)(pC + ks * 512);
                acc[0][nj] = __builtin_amdgcn_mfma_f32_16x16x32_bf16(af[ks], b0, acc[0][nj], 0, 0, 0);
                acc[1][nj] = __builtin_amdgcn_mfma_f32_16x16x32_bf16(af[ks], b1, acc[1][nj], 0, 0, 0);
            }
        }

        float pq[4];
        #pragma unroll
        for (int i = 0; i < 4; i++) {
            const int m = bm + q * 4 + i;
            float p = 0.0f;
            #pragma unroll
            for (int nj = 0; nj < 4; nj++)
                p += x[(size_t)m * FD + wave * 64 + nj * 16 + l16] * acc[0][nj][i];
            #pragma unroll
            for (int off = 1; off < 16; off <<= 1) p += __shfl_xor(p, off);
            pq[i] = p;
        }
        if (l16 == 0) {
            #pragma unroll
            for (int i = 0; i < 4; i++) dsum[wave][q * 4 + i] = pq[i];
        }
        __syncthreads();
        if (tid < 16) dvec[bm + tid] = dsum[0][tid] + dsum[1][tid] + dsum[2][tid] + dsum[3][tid];

        float bcv[4];
        #pragma unroll
        for (int nj = 0; nj < 4; nj++) bcv[nj] = bc[wave * 64 + nj * 16 + l16];

        const int o0 = (n0 >> 3) & 3;
        #pragma unroll
        for (int pass = 0; pass < 2; pass++) {
            __syncthreads();
            #pragma unroll
            for (int nj = 0; nj < 4; nj++)
                #pragma unroll
                for (int i = 0; i < 4; i++) {
                    float v = acc[pass][nj][i];
                    if (pass == 1) v += bcv[nj];
                    TrT[(wave * 64 + nj * 16 + l16) * 24 + q * 4 + i] = (bf16)v;
                }
            __syncthreads();
            bf16* dst = (pass ? U2Tp : abTp) + (size_t)b * FD * NN;
            #pragma unroll
            for (int it = 0; it < 2; it++) {
                int c = tid + it * 256;
                int r = c >> 1, h = c & 1;
                bf16x8 v = *(const bf16x8*)&TrT[r * 24 + h * 8];
                int chunk = (r >> 4) * 32 + (n0 >> 5);
                *(bf16x8*)&dst[(size_t)chunk * 512 + ((o0 + h) * 16 + (r & 15)) * 8] = v;
            }
        }
        publish(&cnt_p[b]);
    }

    // ================= Phase 2: m2 tile (32 low blocks of each 64-group) =================
    // group g = bid>>6 serves batch (g+15)&15 -> waits point to lower ids for g>=1.
    if ((bid & 63) < 32) {
        const int b = ((bid >> 6) + 15) & 15;
        const int tile = bid & 31;
        const int bj = (tile >> 3) * 64, bk = (tile & 7) * 32;

        wait_for(&cnt_p[b], 64);

        const bf16* Ab = U2Tp + (size_t)b * FD * NN + lane * 8;
        const bf16* Bb = abTp + (size_t)b * FD * NN + lane * 8;
        const int ach = ((bj >> 4) + wave) * 32;
        const int bch0 = (bk >> 4) * 32;
        const int bch1 = ((bk >> 4) + 1) * 32;

        floatx4 acc[2] = {};
        #pragma unroll 8
        for (int n5 = 0; n5 < 32; n5++) {
            bf16x8 af = *(const bf16x8*)&Ab[(size_t)(ach + n5) * 512];
            bf16x8 b0 = *(const bf16x8*)&Bb[(size_t)(bch0 + n5) * 512];
            bf16x8 b1 = *(const bf16x8*)&Bb[(size_t)(bch1 + n5) * 512];
            acc[0] = __builtin_amdgcn_mfma_f32_16x16x32_bf16(af, b0, acc[0], 0, 0, 0);
            acc[1] = __builtin_amdgcn_mfma_f32_16x16x32_bf16(af, b1, acc[1], 0, 0, 0);
        }

        #pragma unroll
        for (int i = 0; i < 4; i++)
            #pragma unroll
            for (int kj = 0; kj < 2; kj++)
                Tr[wave * 16 + q * 4 + i][kj * 16 + l16] = (bf16)acc[kj][i];
        __syncthreads();
        {
            const int jj = tid >> 2, oct = tid & 3;
            bf16x8 v = *(const bf16x8*)&Tr[jj][oct * 8];
            const int chunk = ((bj + jj) >> 4) * 8 + (bk >> 5);
            *(bf16x8*)&Gp[(size_t)b * FD * FD + (size_t)chunk * 512
                          + (oct * 16 + ((bj + jj) & 15)) * 8] = v;
        }
        publish(&cnt_m[b]);
    }

    // ================= Phase 3: final tile (batch = bid>>6) =================
    {
        const int b = bid >> 6, t = bid & 63;
        const int bm = b * NN + (t >> 2) * 64, bn = (t & 3) * 64;

        wait_for(&cnt_m[b], 32);

        const float* xr = x + (size_t)(bm + wave * 16 + l16) * FD;
        const bf16* Gb = Gp + (size_t)b * FD * FD + lane * 8;
        const bf16* Wc = WfC + lane * 8;
        const int cb = bn >> 4;

        floatx4 acc[4] = {}, acc2[4] = {};
        #pragma unroll
        for (int ks = 0; ks < 8; ks++) {
            const int ko = ks * 32 + q * 8;
            bf16x8 af = cvt8(*(const float4*)&xr[ko], *(const float4*)&xr[ko + 4]);
            #pragma unroll
            for (int nj = 0; nj < 4; nj++) {
                bf16x8 bg = *(const bf16x8*)&Gb[(size_t)((cb + nj) * 8 + ks) * 512];
                bf16x8 bu = *(const bf16x8*)&Wc[(size_t)((cb + nj) * 8 + ks) * 512];
                acc[nj]  = __builtin_amdgcn_mfma_f32_16x16x32_bf16(af, bg, acc[nj], 0, 0, 0);
                acc2[nj] = __builtin_amdgcn_mfma_f32_16x16x32_bf16(af, bu, acc2[nj], 0, 0, 0);
            }
        }

        float bcv[4];
        #pragma unroll
        for (int nj = 0; nj < 4; nj++) bcv[nj] = bc[bn + nj * 16 + l16];

        #pragma unroll
        for (int i = 0; i < 4; i++) {
            const int m = bm + wave * 16 + q * 4 + i;
            const float d = dvec[m];
            #pragma unroll
            for (int nj = 0; nj < 4; nj++) {
                const int n = bn + nj * 16 + l16;
                const float u2 = acc2[nj][i] + bcv[nj];
                const float v = (acc[nj][i] - d * u2) * (1.0f / 1024.0f);
                out[(size_t)m * FD + n] = v + x[(size_t)m * FD + n];
            }
        }
    }
}

extern "C" void kernel_launch(void* const* d_in, const int* in_sizes, int n_in,
                              void* d_out, int out_size, void* d_ws, size_t ws_size,
                              hipStream_t stream)
{
    const float* x  = (const float*)d_in[0];
    const float* Wa = (const float*)d_in[1];
    const float* Wb = (const float*)d_in[2];
    const float* Wu = (const float*)d_in[3];
    const float* bu = (const float*)d_in[4];
    const float* Wr = (const float*)d_in[5];
    float* out = (float*)d_out;

    char* w = (char*)d_ws;
    bf16* WfC   = (bf16*)w;  w += (size_t)FD * FD * 2;
    bf16* WfA   = (bf16*)w;  w += (size_t)FD * FD * 2;
    float* bc   = (float*)w; w += (size_t)FD * 4;
    bf16* abTp  = (bf16*)w;  w += (size_t)RR * FD * 2;
    bf16* U2Tp  = (bf16*)w;  w += (size_t)RR * FD * 2;
    bf16* Gp    = (bf16*)w;  w += (size_t)NB * FD * FD * 2;
    float* dvec = (float*)w; w += (size_t)RR * 4;
    int* cnt    = (int*)w;   w += 256;

    dim3 blk(256);

    prep<<<dim3(513), blk, 0, stream>>>(Wa, Wb, Wu, bu, Wr, WfC, WfA, bc, cnt);

    fused<<<dim3(1024), blk, 0, stream>>>(x, WfA, WfC, abTp, U2Tp, Gp, bc, dvec, out, cnt);
}